// Round 12
// 407.837 us; speedup vs baseline: 15.0359x; 1.0041x over previous
//
#include <hip/hip_runtime.h>

// B=4, N=4096, C=768, H=12, D=64, M=64, PNP=11, SCALE=1/8

typedef __attribute__((ext_vector_type(8))) short short8;
typedef __attribute__((ext_vector_type(4))) float f32x4;
typedef __attribute__((ext_vector_type(4))) unsigned short ushort4v;

static __device__ __forceinline__ unsigned short f2bf(float f) {
    union { float f; unsigned u; } x; x.f = f;
    unsigned r = x.u + 0x7fffu + ((x.u >> 16) & 1u);   // RNE
    return (unsigned short)(r >> 16);
}

static __device__ __forceinline__ float b2f(unsigned short u) {
    union { unsigned u; float f; } t; t.u = (unsigned)u << 16; return t.f;
}

static __device__ __forceinline__ void bfsplit(float x, unsigned short& h, unsigned short& l) {
    unsigned short hh = f2bf(x);
    union { unsigned u; float f; } t; t.u = (unsigned)hh << 16;
    h = hh;
    l = f2bf(x - t.f);    // exact residual, RNE to bf16
}

// ---------------------------------------------------------------------------
// K0: split 3 fp32 arrays into bf16 (hi,lo) pairs, one fused launch.
// ---------------------------------------------------------------------------
__global__ __launch_bounds__(256) void preconv3(
    const float* __restrict__ a, const float* __restrict__ b,
    const float* __restrict__ c,
    unsigned short* __restrict__ ahi, unsigned short* __restrict__ alo,
    unsigned short* __restrict__ bhi, unsigned short* __restrict__ blo,
    unsigned short* __restrict__ chi, unsigned short* __restrict__ clo)
{
    const int nA = 3145728, nB = 442368, nC = 147456;
    const int total = nA + nB + nC;
    for (int i = blockIdx.x * 256 + threadIdx.x; i < total; i += gridDim.x * 256) {
        const float* src; unsigned short* hi; unsigned short* lo; int j;
        if (i < nA)           { src = a; hi = ahi; lo = alo; j = i; }
        else if (i < nA + nB) { src = b; hi = bhi; lo = blo; j = i - nA; }
        else                  { src = c; hi = chi; lo = clo; j = i - nA - nB; }
        float4 f = *(const float4*)(src + (size_t)j * 4);
        float vs[4] = {f.x, f.y, f.z, f.w};
        ushort4v h, l;
        #pragma unroll
        for (int t = 0; t < 4; ++t) {
            unsigned short hh, ll;
            bfsplit(vs[t], hh, ll);
            h[t] = hh; l[t] = ll;
        }
        *(ushort4v*)(hi + (size_t)j * 4) = h;
        *(ushort4v*)(lo + (size_t)j * 4) = l;
    }
}

// ---------------------------------------------------------------------------
// K1: combined QKV GEMM. blocks [0,1536): qk via bf16x3; [1536,2304): v bf16.
// ---------------------------------------------------------------------------
__global__ __launch_bounds__(256, 2) void gemm_qkv2(
    const unsigned short* __restrict__ Xh, const unsigned short* __restrict__ Xl,
    const unsigned short* __restrict__ Wh, const unsigned short* __restrict__ Wl,
    const float* __restrict__ bias,
    unsigned short* __restrict__ qh, unsigned short* __restrict__ ql,
    unsigned short* __restrict__ kh, unsigned short* __restrict__ kl,
    unsigned short* __restrict__ vh)
{
    __shared__ unsigned short smem[16384];   // 32 KB
    const int tid = threadIdx.x;
    const int ln = tid & 63, wv = tid >> 6;
    const int wr = (wv >> 1) << 6, wc = (wv & 1) << 6;
    const int fr = ln & 15, fc = ln >> 4;
    const int fg = ln >> 4;

    if (blockIdx.x < 1536) {
        unsigned short* Ah = smem;
        unsigned short* Al = smem + 4096;
        unsigned short* Bh = smem + 8192;
        unsigned short* Bl = smem + 12288;
        const int bid = blockIdx.x;
        const int swz = (bid & 7) * 192 + (bid >> 3);
        const int brow = (swz / 12) << 7, bcol = (swz % 12) << 7;
        const int srow = tid >> 1, sc = (tid & 1) << 1;
        const size_t ag = (size_t)(brow + srow) * 768 + (sc << 3);
        const size_t bg = (size_t)(bcol + srow) * 768 + (sc << 3);
        const int i0 = srow * 32 + (((sc + 0) ^ (srow & 3)) << 3);
        const int i1 = srow * 32 + (((sc + 1) ^ (srow & 3)) << 3);

        f32x4 acc[4][4] = {};
        for (int k0 = 0; k0 < 768; k0 += 32) {
            short8 xh0 = *(const short8*)(Xh + ag + k0);
            short8 xh1 = *(const short8*)(Xh + ag + k0 + 8);
            short8 xl0 = *(const short8*)(Xl + ag + k0);
            short8 xl1 = *(const short8*)(Xl + ag + k0 + 8);
            short8 wh0 = *(const short8*)(Wh + bg + k0);
            short8 wh1 = *(const short8*)(Wh + bg + k0 + 8);
            short8 wl0 = *(const short8*)(Wl + bg + k0);
            short8 wl1 = *(const short8*)(Wl + bg + k0 + 8);
            __syncthreads();
            *(short8*)&Ah[i0] = xh0; *(short8*)&Ah[i1] = xh1;
            *(short8*)&Al[i0] = xl0; *(short8*)&Al[i1] = xl1;
            *(short8*)&Bh[i0] = wh0; *(short8*)&Bh[i1] = wh1;
            *(short8*)&Bl[i0] = wl0; *(short8*)&Bl[i1] = wl1;
            __syncthreads();
            short8 ah[4], al[4], bh[4], bl[4];
            #pragma unroll
            for (int i = 0; i < 4; ++i) {
                int ar = wr + (i << 4) + fr;
                int aidx = ar * 32 + ((fc ^ (ar & 3)) << 3);
                ah[i] = *(short8*)&Ah[aidx];
                al[i] = *(short8*)&Al[aidx];
                int br2 = wc + (i << 4) + fr;
                int bidx = br2 * 32 + ((fc ^ (br2 & 3)) << 3);
                bh[i] = *(short8*)&Bh[bidx];
                bl[i] = *(short8*)&Bl[bidx];
            }
            #pragma unroll
            for (int i = 0; i < 4; ++i)
                #pragma unroll
                for (int j = 0; j < 4; ++j) {
                    acc[i][j] = __builtin_amdgcn_mfma_f32_16x16x32_bf16(ah[i], bh[j], acc[i][j], 0, 0, 0);
                    acc[i][j] = __builtin_amdgcn_mfma_f32_16x16x32_bf16(ah[i], bl[j], acc[i][j], 0, 0, 0);
                    acc[i][j] = __builtin_amdgcn_mfma_f32_16x16x32_bf16(al[i], bh[j], acc[i][j], 0, 0, 0);
                }
        }
        #pragma unroll
        for (int j = 0; j < 4; ++j) {
            int c = bcol + wc + (j << 4) + fr;
            float bb = bias[c];
            int rem = c - (c >= 768 ? 768 : 0);
            int h = rem >> 6, d = rem & 63;
            #pragma unroll
            for (int i = 0; i < 4; ++i)
                #pragma unroll
                for (int r = 0; r < 4; ++r) {
                    int row = brow + wr + (i << 4) + (fg << 2) + r;
                    int b = row >> 12, n = row & 4095;
                    float val = acc[i][j][r] + bb;
                    size_t idx = (((size_t)(b * 12 + h) << 12) + n) * 64 + d;
                    unsigned short hh, ll;
                    if (c < 768) {
                        bfsplit(val * 0.125f, hh, ll);
                        qh[idx] = hh; ql[idx] = ll;
                    } else {
                        bfsplit(val, hh, ll);
                        kh[idx] = hh; kl[idx] = ll;
                    }
                }
        }
    } else {
        unsigned short* Av = smem;            // [128][64]
        unsigned short* Bv = smem + 8192;
        const int bid = blockIdx.x - 1536;
        const int swz = (bid & 7) * 96 + (bid >> 3);
        const int brow = (swz / 6) << 7, bcol = 1536 + ((swz % 6) << 7);
        const int srow = tid >> 1;
        const int c0 = (tid & 1) << 2;
        const size_t ag = (size_t)(brow + srow) * 768;
        const size_t bg = (size_t)(bcol + srow) * 768;

        f32x4 acc[4][4] = {};
        for (int k0 = 0; k0 < 768; k0 += 64) {
            short8 xa[4], wb[4];
            #pragma unroll
            for (int cc = 0; cc < 4; ++cc) {
                xa[cc] = *(const short8*)(Xh + ag + k0 + ((c0 + cc) << 3));
                wb[cc] = *(const short8*)(Wh + bg + k0 + ((c0 + cc) << 3));
            }
            __syncthreads();
            #pragma unroll
            for (int cc = 0; cc < 4; ++cc) {
                int dst = srow * 64 + (((c0 + cc) ^ (srow & 7)) << 3);
                *(short8*)&Av[dst] = xa[cc];
                *(short8*)&Bv[dst] = wb[cc];
            }
            __syncthreads();
            #pragma unroll
            for (int ks = 0; ks < 2; ++ks) {
                const int kc = (ks << 2) + fc;
                short8 ah[4], bh[4];
                #pragma unroll
                for (int i = 0; i < 4; ++i) {
                    int ar = wr + (i << 4) + fr;
                    ah[i] = *(short8*)&Av[ar * 64 + ((kc ^ (ar & 7)) << 3)];
                    int br2 = wc + (i << 4) + fr;
                    bh[i] = *(short8*)&Bv[br2 * 64 + ((kc ^ (br2 & 7)) << 3)];
                }
                #pragma unroll
                for (int i = 0; i < 4; ++i)
                    #pragma unroll
                    for (int j = 0; j < 4; ++j)
                        acc[i][j] = __builtin_amdgcn_mfma_f32_16x16x32_bf16(ah[i], bh[j], acc[i][j], 0, 0, 0);
            }
        }
        #pragma unroll
        for (int j = 0; j < 4; ++j) {
            int c = bcol + wc + (j << 4) + fr;
            float bb = bias[c];
            int rem = c - 1536;
            int h = rem >> 6, d = rem & 63;
            #pragma unroll
            for (int i = 0; i < 4; ++i)
                #pragma unroll
                for (int r = 0; r < 4; ++r) {
                    int row = brow + wr + (i << 4) + (fg << 2) + r;
                    int b = row >> 12, n = row & 4095;
                    float val = acc[i][j][r] + bb;
                    size_t idx = (((size_t)(b * 12 + h) << 12) + n) * 64 + d;
                    vh[idx] = f2bf(val);
                }
        }
    }
}

// ---------------------------------------------------------------------------
// K2: attn_mega — blocks [0,1024): flash_part (h=11); [1024,1376): wflash.
// ---------------------------------------------------------------------------
__global__ __launch_bounds__(256) void attn_mega(
    const unsigned short* __restrict__ qh, const unsigned short* __restrict__ ql,
    const unsigned short* __restrict__ khg, const unsigned short* __restrict__ klg,
    const unsigned short* __restrict__ vhg,
    float* __restrict__ wacc, float* __restrict__ wl, float* __restrict__ wm,
    float* __restrict__ pacc, float* __restrict__ pm, float* __restrict__ pl)
{
    __shared__ unsigned short kh_s[64][72], kl_s[64][72];
    __shared__ unsigned short vth[64][72];
    __shared__ unsigned short ph[4][16][72];
    int tid = threadIdx.x;
    int wv = tid >> 6, ln = tid & 63;
    int rr = tid >> 2, dg = (tid & 3) << 4;
    const int arow = (wv << 4) + (ln & 15);
    const int ak0 = (ln >> 4) << 3;
    const int rg = (ln >> 4) << 2;

    if (blockIdx.x < 1024) {
        int fbid = blockIdx.x;
        int bx = fbid & 63, cy = (fbid >> 6) & 3, b = fbid >> 8;
        int n0 = bx << 6;
        size_t base = ((size_t)(b * 12 + 11)) << 12;
        {
            size_t off = ((base + n0 + rr) << 6) + dg;
            *(short8*)&kh_s[rr][dg]     = *(const short8*)(qh + off);
            *(short8*)&kh_s[rr][dg + 8] = *(const short8*)(qh + off + 8);
        }
        __syncthreads();
        short8 aq0 = *(short8*)&kh_s[arow][ak0];
        short8 aq1 = *(short8*)&kh_s[arow][ak0 + 32];
        f32x4 o_acc[4] = {};
        float mr[4] = {-1e30f, -1e30f, -1e30f, -1e30f};
        float lr[4] = {};
        for (int t = 0; t < 16; ++t) {
            int m0 = (cy << 10) + (t << 6);
            __syncthreads();
            {
                size_t off = ((base + m0 + rr) << 6) + dg;
                *(short8*)&kl_s[rr][dg]     = *(const short8*)(khg + off);
                *(short8*)&kl_s[rr][dg + 8] = *(const short8*)(khg + off + 8);
                short8 v0 = *(const short8*)(vhg + off);
                short8 v1 = *(const short8*)(vhg + off + 8);
                #pragma unroll
                for (int i = 0; i < 8; ++i) {
                    vth[dg + i][rr]     = (unsigned short)v0[i];
                    vth[dg + 8 + i][rr] = (unsigned short)v1[i];
                }
            }
            __syncthreads();
            f32x4 s_acc[4];
            #pragma unroll
            for (int jb = 0; jb < 4; ++jb) {
                f32x4 z = {};
                short8 bk0 = *(short8*)&kl_s[(jb << 4) + (ln & 15)][ak0];
                short8 bk1 = *(short8*)&kl_s[(jb << 4) + (ln & 15)][ak0 + 32];
                z = __builtin_amdgcn_mfma_f32_16x16x32_bf16(aq0, bk0, z, 0, 0, 0);
                z = __builtin_amdgcn_mfma_f32_16x16x32_bf16(aq1, bk1, z, 0, 0, 0);
                s_acc[jb] = z;
            }
            float mx[4];
            #pragma unroll
            for (int r = 0; r < 4; ++r)
                mx[r] = fmaxf(fmaxf(s_acc[0][r], s_acc[1][r]),
                              fmaxf(s_acc[2][r], s_acc[3][r]));
            #pragma unroll
            for (int off2 = 1; off2 < 16; off2 <<= 1)
                #pragma unroll
                for (int r = 0; r < 4; ++r)
                    mx[r] = fmaxf(mx[r], __shfl_xor(mx[r], off2, 64));
            float fac[4];
            #pragma unroll
            for (int r = 0; r < 4; ++r) {
                float mn = fmaxf(mr[r], mx[r]);
                fac[r] = expf(mr[r] - mn);
                mr[r] = mn;
            }
            float rs[4] = {};
            #pragma unroll
            for (int jb = 0; jb < 4; ++jb)
                #pragma unroll
                for (int r = 0; r < 4; ++r) {
                    float p = expf(s_acc[jb][r] - mr[r]);
                    rs[r] += p;
                    ph[wv][rg + r][(jb << 4) + (ln & 15)] = f2bf(p);
                }
            #pragma unroll
            for (int off2 = 1; off2 < 16; off2 <<= 1)
                #pragma unroll
                for (int r = 0; r < 4; ++r)
                    rs[r] += __shfl_xor(rs[r], off2, 64);
            #pragma unroll
            for (int r = 0; r < 4; ++r) lr[r] = lr[r] * fac[r] + rs[r];
            #pragma unroll
            for (int jb = 0; jb < 4; ++jb)
                #pragma unroll
                for (int r = 0; r < 4; ++r)
                    o_acc[jb][r] *= fac[r];
            short8 pa0 = *(short8*)&ph[wv][ln & 15][ak0];
            short8 pa1 = *(short8*)&ph[wv][ln & 15][ak0 + 32];
            #pragma unroll
            for (int jb = 0; jb < 4; ++jb) {
                short8 bv0 = *(short8*)&vth[(jb << 4) + (ln & 15)][ak0];
                short8 bv1 = *(short8*)&vth[(jb << 4) + (ln & 15)][ak0 + 32];
                f32x4 z = o_acc[jb];
                z = __builtin_amdgcn_mfma_f32_16x16x32_bf16(pa0, bv0, z, 0, 0, 0);
                z = __builtin_amdgcn_mfma_f32_16x16x32_bf16(pa1, bv1, z, 0, 0, 0);
                o_acc[jb] = z;
            }
        }
        int slot = (b * 4 + cy) * 64 + bx;
        #pragma unroll
        for (int jb = 0; jb < 4; ++jb)
            #pragma unroll
            for (int r = 0; r < 4; ++r) {
                int row = (wv << 4) + rg + r, col = (jb << 4) + (ln & 15);
                pacc[(size_t)slot * 4096 + (size_t)row * 64 + col] = o_acc[jb][r];
            }
        if ((ln & 15) == 0)
            #pragma unroll
            for (int r = 0; r < 4; ++r) {
                int row = (wv << 4) + rg + r;
                pm[(size_t)slot * 64 + row] = mr[r];
                pl[(size_t)slot * 64 + row] = lr[r];
            }
    } else {
        int wbid = blockIdx.x - 1024;
        int chunk = wbid & 7;
        int bh = wbid >> 3;
        int b = bh / 11, h = bh - b * 11;
        size_t base = ((size_t)(b * 12 + h)) << 12;
        short8 aqh0, aql0, aqh1, aql1;
        {
            size_t off = ((base + ((size_t)arow << 6)) << 6) + ak0;
            aqh0 = *(const short8*)(qh + off);
            aqh1 = *(const short8*)(qh + off + 32);
            aql0 = *(const short8*)(ql + off);
            aql1 = *(const short8*)(ql + off + 32);
        }
        f32x4 o_acc[4] = {};
        float mr[4] = {-1e30f, -1e30f, -1e30f, -1e30f};
        float lr[4] = {};
        for (int t = 0; t < 8; ++t) {
            int n0 = (chunk << 9) + (t << 6);
            __syncthreads();
            {
                size_t off = ((base + n0 + rr) << 6) + dg;
                *(short8*)&kh_s[rr][dg]     = *(const short8*)(khg + off);
                *(short8*)&kh_s[rr][dg + 8] = *(const short8*)(khg + off + 8);
                *(short8*)&kl_s[rr][dg]     = *(const short8*)(klg + off);
                *(short8*)&kl_s[rr][dg + 8] = *(const short8*)(klg + off + 8);
                short8 v0 = *(const short8*)(vhg + off);
                short8 v1 = *(const short8*)(vhg + off + 8);
                #pragma unroll
                for (int i = 0; i < 8; ++i) {
                    vth[dg + i][rr]     = (unsigned short)v0[i];
                    vth[dg + 8 + i][rr] = (unsigned short)v1[i];
                }
            }
            __syncthreads();
            f32x4 s_acc[4];
            #pragma unroll
            for (int jb = 0; jb < 4; ++jb) {
                f32x4 z = {};
                const int brow2 = (jb << 4) + (ln & 15);
                short8 bh0 = *(short8*)&kh_s[brow2][ak0];
                short8 bh1 = *(short8*)&kh_s[brow2][ak0 + 32];
                short8 bl0 = *(short8*)&kl_s[brow2][ak0];
                short8 bl1 = *(short8*)&kl_s[brow2][ak0 + 32];
                z = __builtin_amdgcn_mfma_f32_16x16x32_bf16(aqh0, bh0, z, 0, 0, 0);
                z = __builtin_amdgcn_mfma_f32_16x16x32_bf16(aqh0, bl0, z, 0, 0, 0);
                z = __builtin_amdgcn_mfma_f32_16x16x32_bf16(aql0, bh0, z, 0, 0, 0);
                z = __builtin_amdgcn_mfma_f32_16x16x32_bf16(aqh1, bh1, z, 0, 0, 0);
                z = __builtin_amdgcn_mfma_f32_16x16x32_bf16(aqh1, bl1, z, 0, 0, 0);
                z = __builtin_amdgcn_mfma_f32_16x16x32_bf16(aql1, bh1, z, 0, 0, 0);
                s_acc[jb] = z;
            }
            float mx[4];
            #pragma unroll
            for (int r = 0; r < 4; ++r)
                mx[r] = fmaxf(fmaxf(s_acc[0][r], s_acc[1][r]),
                              fmaxf(s_acc[2][r], s_acc[3][r]));
            #pragma unroll
            for (int off2 = 1; off2 < 16; off2 <<= 1)
                #pragma unroll
                for (int r = 0; r < 4; ++r)
                    mx[r] = fmaxf(mx[r], __shfl_xor(mx[r], off2, 64));
            float fac[4];
            #pragma unroll
            for (int r = 0; r < 4; ++r) {
                float mn = fmaxf(mr[r], mx[r]);
                fac[r] = expf(mr[r] - mn);
                mr[r] = mn;
            }
            float rs[4] = {};
            #pragma unroll
            for (int jb = 0; jb < 4; ++jb)
                #pragma unroll
                for (int r = 0; r < 4; ++r) {
                    float p = expf(s_acc[jb][r] - mr[r]);
                    rs[r] += p;
                    ph[wv][rg + r][(jb << 4) + (ln & 15)] = f2bf(p);
                }
            #pragma unroll
            for (int off2 = 1; off2 < 16; off2 <<= 1)
                #pragma unroll
                for (int r = 0; r < 4; ++r)
                    rs[r] += __shfl_xor(rs[r], off2, 64);
            #pragma unroll
            for (int r = 0; r < 4; ++r) lr[r] = lr[r] * fac[r] + rs[r];
            #pragma unroll
            for (int jb = 0; jb < 4; ++jb)
                #pragma unroll
                for (int r = 0; r < 4; ++r)
                    o_acc[jb][r] *= fac[r];
            short8 pah0 = *(short8*)&ph[wv][ln & 15][ak0];
            short8 pah1 = *(short8*)&ph[wv][ln & 15][ak0 + 32];
            #pragma unroll
            for (int jb = 0; jb < 4; ++jb) {
                const int brow2 = (jb << 4) + (ln & 15);
                short8 bv0 = *(short8*)&vth[brow2][ak0];
                short8 bv1 = *(short8*)&vth[brow2][ak0 + 32];
                f32x4 o = o_acc[jb];
                o = __builtin_amdgcn_mfma_f32_16x16x32_bf16(pah0, bv0, o, 0, 0, 0);
                o = __builtin_amdgcn_mfma_f32_16x16x32_bf16(pah1, bv1, o, 0, 0, 0);
                o_acc[jb] = o;
            }
        }
        int cidx = (bh << 3) + chunk;
        #pragma unroll
        for (int jb = 0; jb < 4; ++jb)
            #pragma unroll
            for (int r = 0; r < 4; ++r) {
                int row = (wv << 4) + rg + r, col = (jb << 4) + (ln & 15);
                wacc[((size_t)cidx << 12) + ((size_t)row << 6) + col] = o_acc[jb][r];
            }
        if ((ln & 15) == 0)
            #pragma unroll
            for (int r = 0; r < 4; ++r) {
                int row = (wv << 4) + rg + r;
                wl[cidx * 64 + row] = lr[r];
                wm[cidx * 64 + row] = mr[r];
            }
    }
}

// ---------------------------------------------------------------------------
// K3: fused wmerge + eB + norms. One block per bh; per-head maxima via
// atomicMax on uint-encoded positive floats (denr/denc pre-zeroed).
// ---------------------------------------------------------------------------
__global__ __launch_bounds__(256) void wmerge_eb(
    const float* __restrict__ wacc, const float* __restrict__ wl,
    const float* __restrict__ wm,
    const unsigned short* __restrict__ qh, const unsigned short* __restrict__ ql,
    const unsigned short* __restrict__ kh, const unsigned short* __restrict__ kl,
    float* __restrict__ Wb, float* __restrict__ eB,
    float* __restrict__ denr, float* __restrict__ denc)
{
    int bh = blockIdx.x;
    int b = bh / 11, h = bh - b * 11;
    size_t base = ((size_t)(b * 12 + h)) << 12;
    int tid = threadIdx.x;
    __shared__ float fcs[8][64];
    __shared__ float scms[64];
    __shared__ float qm[64][65], km[64][65];
    __shared__ float ebs[64][65];
    for (int e = tid; e < 4096; e += 256) {
        int mm = e >> 6, d = e & 63;
        size_t off = ((base + ((size_t)mm << 6)) << 6) + d;
        qm[mm][d] = b2f(qh[off]) + b2f(ql[off]);
        km[mm][d] = b2f(kh[off]) + b2f(kl[off]);
    }
    if (tid < 64) {
        float mx = -1e30f;
        #pragma unroll
        for (int c = 0; c < 8; ++c)
            mx = fmaxf(mx, wm[((bh << 3) + c) * 64 + tid]);
        scms[tid] = mx;
        #pragma unroll
        for (int c = 0; c < 8; ++c)
            fcs[c][tid] = expf(wm[((bh << 3) + c) * 64 + tid] - mx);
    }
    __syncthreads();
    for (int e = tid; e < 4096; e += 256) {
        int m = e >> 6, j = e & 63;
        float s = 0.f;
        #pragma unroll
        for (int c = 0; c < 8; ++c)
            s += fcs[c][m] * wacc[((size_t)((bh << 3) + c) << 12) + e];
        Wb[(size_t)bh * 4160 + m * 65 + j] = s;
    }
    if (tid < 64) {
        float s = 0.f;
        #pragma unroll
        for (int c = 0; c < 8; ++c)
            s += fcs[c][tid] * wl[((bh << 3) + c) * 64 + tid];
        Wb[(size_t)bh * 4160 + tid * 65 + 64] = s;
    }
    // eB phase
    int m = tid >> 2, l0 = tid & 3;
    float smax = scms[m];
    for (int l = l0; l < 64; l += 4) {
        float s = 0.f;
        #pragma unroll
        for (int d = 0; d < 64; ++d) s += qm[m][d] * km[l][d];
        float ev = expf(fmaxf(s - smax, -88.f));
        eB[((size_t)bh << 12) + (m << 6) + l] = ev;
        ebs[m][l] = ev;
    }
    __syncthreads();
    // norms phase: row/col sums + block max -> per-head atomicMax
    if (tid < 64) {
        float rs = 0.f, cs = 0.f;
        #pragma unroll 4
        for (int l = 0; l < 64; ++l) rs += ebs[tid][l];
        #pragma unroll 4
        for (int mm = 0; mm < 64; ++mm) cs += ebs[mm][tid];
        float rmax = rs, cmax = cs;
        #pragma unroll
        for (int off = 1; off < 64; off <<= 1) {
            rmax = fmaxf(rmax, __shfl_xor(rmax, off, 64));
            cmax = fmaxf(cmax, __shfl_xor(cmax, off, 64));
        }
        if (tid == 0) {
            atomicMax((unsigned*)&denr[h], __float_as_uint(rmax));
            atomicMax((unsigned*)&denc[h], __float_as_uint(cmax));
        }
    }
}

// ---------------------------------------------------------------------------
// K4: pinv (6 Newton iterations, bf16x3 MFMA) fused with pw: T = pi@W.
// ---------------------------------------------------------------------------
__device__ __forceinline__ void mm64x3(
    const unsigned short (&Ahi)[64][72], const unsigned short (&Alo)[64][72],
    const unsigned short (&BThi)[64][72], const unsigned short (&BTlo)[64][72],
    int wr, int wc, int fr, int fk, f32x4 (&acc)[2][2])
{
    #pragma unroll
    for (int ks = 0; ks < 2; ++ks) {
        const int kb = (ks << 5) + fk;
        short8 ah[2], al[2], bh[2], bl[2];
        #pragma unroll
        for (int i = 0; i < 2; ++i) {
            ah[i] = *(const short8*)&Ahi[wr + (i << 4) + fr][kb];
            al[i] = *(const short8*)&Alo[wr + (i << 4) + fr][kb];
            bh[i] = *(const short8*)&BThi[wc + (i << 4) + fr][kb];
            bl[i] = *(const short8*)&BTlo[wc + (i << 4) + fr][kb];
        }
        #pragma unroll
        for (int i = 0; i < 2; ++i)
            #pragma unroll
            for (int j = 0; j < 2; ++j) {
                acc[i][j] = __builtin_amdgcn_mfma_f32_16x16x32_bf16(ah[i], bh[j], acc[i][j], 0, 0, 0);
                acc[i][j] = __builtin_amdgcn_mfma_f32_16x16x32_bf16(ah[i], bl[j], acc[i][j], 0, 0, 0);
                acc[i][j] = __builtin_amdgcn_mfma_f32_16x16x32_bf16(al[i], bh[j], acc[i][j], 0, 0, 0);
            }
    }
}

__global__ __launch_bounds__(256) void pinv_pw(
    const float* __restrict__ eB,
    const float* __restrict__ denr, const float* __restrict__ denc,
    const float* __restrict__ Wb, float* __restrict__ Tb)
{
    __shared__ unsigned short Xh[64][72],  Xl[64][72];
    __shared__ unsigned short Zh[64][72],  Zl[64][72];
    __shared__ unsigned short ZTh[64][72], ZTl[64][72];
    __shared__ unsigned short Mh[64][72],  Ml[64][72];
    __shared__ unsigned short MTh[64][72], MTl[64][72];
    __shared__ unsigned short Th[64][72],  Tbl[64][72];
    __shared__ float Zf[64][69];
    __shared__ float Wls[64][66];
    int bh = blockIdx.x;
    int h = bh % 11;
    int tid = threadIdx.x;
    float dn = denr[h] * denc[h];
    const int ln = tid & 63, wv = tid >> 6;
    const int wr = (wv >> 1) << 5, wc = (wv & 1) << 5;
    const int fr = ln & 15, fk = (ln >> 4) << 3;
    const int rg = (ln >> 4) << 2;

    for (int e = tid; e < 4160; e += 256) {
        int l = e / 65, j = e - l * 65;
        Wls[l][j] = Wb[(size_t)bh * 4160 + e];
    }
    for (int e = tid; e < 4096; e += 256) {
        int m = e >> 6, l = e & 63;
        float xv = eB[((size_t)bh << 12) + e];
        unsigned short hh, ll;
        bfsplit(xv, hh, ll);
        Xh[m][l] = hh; Xl[m][l] = ll;
        float zv = xv / dn;
        Zf[l][m] = zv;
        bfsplit(zv, hh, ll);
        Zh[l][m] = hh; Zl[l][m] = ll;
        ZTh[m][l] = hh; ZTl[m][l] = ll;
    }
    __syncthreads();

    for (int it = 0; it < 6; ++it) {
        f32x4 mm1[2][2] = {};
        mm64x3(Xh, Xl, ZTh, ZTl, wr, wc, fr, fk, mm1);
        #pragma unroll
        for (int i = 0; i < 2; ++i)
            #pragma unroll
            for (int j = 0; j < 2; ++j)
                #pragma unroll
                for (int r = 0; r < 4; ++r) {
                    int row = wr + (i << 4) + rg + r, col = wc + (j << 4) + fr;
                    unsigned short hh, ll;
                    bfsplit(mm1[i][j][r], hh, ll);
                    Mh[row][col] = hh;  Ml[row][col] = ll;
                    MTh[col][row] = hh; MTl[col][row] = ll;
                }
        __syncthreads();
        f32x4 a2[2][2] = {};
        mm64x3(Mh, Ml, MTh, MTl, wr, wc, fr, fk, a2);
        #pragma unroll
        for (int i = 0; i < 2; ++i)
            #pragma unroll
            for (int j = 0; j < 2; ++j)
                #pragma unroll
                for (int r = 0; r < 4; ++r) {
                    int row = wr + (i << 4) + rg + r, col = wc + (j << 4) + fr;
                    float val = 7.f * mm1[i][j][r] - a2[i][j][r];
                    unsigned short hh, ll;
                    bfsplit(val, hh, ll);
                    Th[col][row] = hh; Tbl[col][row] = ll;
                }
        __syncthreads();
        f32x4 a3[2][2] = {};
        mm64x3(Mh, Ml, Th, Tbl, wr, wc, fr, fk, a3);
        __syncthreads();
        #pragma unroll
        for (int i = 0; i < 2; ++i)
            #pragma unroll
            for (int j = 0; j < 2; ++j)
                #pragma unroll
                for (int r = 0; r < 4; ++r) {
                    int row = wr + (i << 4) + rg + r, col = wc + (j << 4) + fr;
                    float val = 15.f * mm1[i][j][r] - a3[i][j][r];
                    unsigned short hh, ll;
                    bfsplit(val, hh, ll);
                    Th[col][row] = hh; Tbl[col][row] = ll;
                }
        __syncthreads();
        f32x4 a4[2][2] = {};
        mm64x3(Zh, Zl, Th, Tbl, wr, wc, fr, fk, a4);
        float zn[2][2][4];
        #pragma unroll
        for (int i = 0; i < 2; ++i)
            #pragma unroll
            for (int j = 0; j < 2; ++j)
                #pragma unroll
                for (int r = 0; r < 4; ++r) {
                    int row = wr + (i << 4) + rg + r, col = wc + (j << 4) + fr;
                    zn[i][j][r] = 0.25f * (13.f * Zf[row][col] - a4[i][j][r]);
                }
        __syncthreads();
        #pragma unroll
        for (int i = 0; i < 2; ++i)
            #pragma unroll
            for (int j = 0; j < 2; ++j)
                #pragma unroll
                for (int r = 0; r < 4; ++r) {
                    int row = wr + (i << 4) + rg + r, col = wc + (j << 4) + fr;
                    float val = zn[i][j][r];
                    Zf[row][col] = val;
                    unsigned short hh, ll;
                    bfsplit(val, hh, ll);
                    Zh[row][col] = hh;  Zl[row][col] = ll;
                    ZTh[col][row] = hh; ZTl[col][row] = ll;
                }
        __syncthreads();
    }
    // pw phase: T = Zf(pi) @ Wls
    int m2 = tid & 63, g2 = tid >> 6;
    #pragma unroll
    for (int t = 0; t < 17; ++t) {
        int j = g2 + (t << 2);
        if (j > 64) break;
        float s = 0.f;
        #pragma unroll
        for (int l = 0; l < 64; ++l) s += Zf[m2][l] * Wls[l][j];
        Tb[(size_t)((bh << 6) + m2) * 65 + j] = s;
    }
}

// ---------------------------------------------------------------------------
// K6: combined out_p [0,2816) + flash_merge [2816,3072)
// ---------------------------------------------------------------------------
__global__ __launch_bounds__(256) void outp_merge(
    const unsigned short* __restrict__ qh, const unsigned short* __restrict__ ql,
    const unsigned short* __restrict__ khg, const unsigned short* __restrict__ klg,
    const float* __restrict__ Tb,
    const float* __restrict__ pacc, const float* __restrict__ pm,
    const float* __restrict__ pl,
    unsigned short* __restrict__ ctxh)
{
    int tid = threadIdx.x;
    if (blockIdx.x < 2816) {
        int bh = blockIdx.x >> 6;
        int bx = blockIdx.x & 63;
        int b = bh / 11, h = bh - b * 11;
        int n0 = bx << 6;
        size_t base = ((size_t)(b * 12 + h)) << 12;
        __shared__ unsigned short kmh[64][72], kml[64][72];
        __shared__ unsigned short tth[64][72], ttl[64][72];
        __shared__ unsigned short ph[4][16][72];
        __shared__ float t64[64];
        int wv = tid >> 6, ln = tid & 63;
        int rr = tid >> 2, dg = (tid & 3) << 4;
        const int arow = (wv << 4) + (ln & 15);
        const int ak0 = (ln >> 4) << 3;
        const int rg = (ln >> 4) << 2;
        {
            size_t off = ((base + ((size_t)rr << 6)) << 6) + dg;
            *(short8*)&kmh[rr][dg]     = *(const short8*)(khg + off);
            *(short8*)&kmh[rr][dg + 8] = *(const short8*)(khg + off + 8);
            *(short8*)&kml[rr][dg]     = *(const short8*)(klg + off);
            *(short8*)&kml[rr][dg + 8] = *(const short8*)(klg + off + 8);
        }
        for (int e = tid; e < 4096; e += 256) {
            int m = e >> 6, j = e & 63;
            float tv = Tb[(size_t)((bh << 6) + m) * 65 + j];
            unsigned short hh, ll;
            bfsplit(tv, hh, ll);
            tth[j][m] = hh; ttl[j][m] = ll;
        }
        if (tid < 64) t64[tid] = Tb[(size_t)((bh << 6) + tid) * 65 + 64];
        short8 aqh0, aql0, aqh1, aql1;
        {
            size_t off = ((base + n0 + arow) << 6) + ak0;
            aqh0 = *(const short8*)(qh + off);
            aqh1 = *(const short8*)(qh + off + 32);
            aql0 = *(const short8*)(ql + off);
            aql1 = *(const short8*)(ql + off + 32);
        }
        __syncthreads();
        f32x4 s_acc[4];
        #pragma unroll
        for (int jb = 0; jb < 4; ++jb) {
            f32x4 z = {};
            const int brow2 = (jb << 4) + (ln & 15);
            short8 bh0 = *(short8*)&kmh[brow2][ak0];
            short8 bh1 = *(short8*)&kmh[brow2][ak0 + 32];
            short8 bl0 = *(short8*)&kml[brow2][ak0];
            short8 bl1 = *(short8*)&kml[brow2][ak0 + 32];
            z = __builtin_amdgcn_mfma_f32_16x16x32_bf16(aqh0, bh0, z, 0, 0, 0);
            z = __builtin_amdgcn_mfma_f32_16x16x32_bf16(aqh0, bl0, z, 0, 0, 0);
            z = __builtin_amdgcn_mfma_f32_16x16x32_bf16(aql0, bh0, z, 0, 0, 0);
            z = __builtin_amdgcn_mfma_f32_16x16x32_bf16(aqh1, bh1, z, 0, 0, 0);
            z = __builtin_amdgcn_mfma_f32_16x16x32_bf16(aqh1, bl1, z, 0, 0, 0);
            z = __builtin_amdgcn_mfma_f32_16x16x32_bf16(aql1, bh1, z, 0, 0, 0);
            s_acc[jb] = z;
        }
        float mx[4];
        #pragma unroll
        for (int r = 0; r < 4; ++r)
            mx[r] = fmaxf(fmaxf(s_acc[0][r], s_acc[1][r]),
                          fmaxf(s_acc[2][r], s_acc[3][r]));
        #pragma unroll
        for (int off2 = 1; off2 < 16; off2 <<= 1)
            #pragma unroll
            for (int r = 0; r < 4; ++r)
                mx[r] = fmaxf(mx[r], __shfl_xor(mx[r], off2, 64));
        float den[4] = {};
        #pragma unroll
        for (int jb = 0; jb < 4; ++jb) {
            float tj = t64[(jb << 4) + (ln & 15)];
            #pragma unroll
            for (int r = 0; r < 4; ++r) {
                float p = expf(s_acc[jb][r] - mx[r]);
                den[r] += p * tj;
                ph[wv][rg + r][(jb << 4) + (ln & 15)] = f2bf(p);
            }
        }
        #pragma unroll
        for (int off2 = 1; off2 < 16; off2 <<= 1)
            #pragma unroll
            for (int r = 0; r < 4; ++r)
                den[r] += __shfl_xor(den[r], off2, 64);
        short8 pah0 = *(short8*)&ph[wv][ln & 15][ak0];
        short8 pah1 = *(short8*)&ph[wv][ln & 15][ak0 + 32];
        f32x4 o_acc[4] = {};
        #pragma unroll
        for (int jb = 0; jb < 4; ++jb) {
            const int brow2 = (jb << 4) + (ln & 15);
            short8 bth0 = *(short8*)&tth[brow2][ak0];
            short8 bth1 = *(short8*)&tth[brow2][ak0 + 32];
            short8 btl0 = *(short8*)&ttl[brow2][ak0];
            short8 btl1 = *(short8*)&ttl[brow2][ak0 + 32];
            f32x4 o = o_acc[jb];
            o = __builtin_amdgcn_mfma_f32_16x16x32_bf16(pah0, bth0, o, 0, 0, 0);
            o = __builtin_amdgcn_mfma_f32_16x16x32_bf16(pah0, btl0, o, 0, 0, 0);
            o = __builtin_amdgcn_mfma_f32_16x16x32_bf16(pah1, bth1, o, 0, 0, 0);
            o = __builtin_amdgcn_mfma_f32_16x16x32_bf16(pah1, btl1, o, 0, 0, 0);
            o_acc[jb] = o;
        }
        float inv[4];
        #pragma unroll
        for (int r = 0; r < 4; ++r) inv[r] = 1.0f / fmaxf(den[r], 1e-8f);
        #pragma unroll
        for (int jb = 0; jb < 4; ++jb)
            #pragma unroll
            for (int r = 0; r < 4; ++r) {
                int row = n0 + (wv << 4) + rg + r;
                int col = (jb << 4) + (ln & 15);
                ctxh[((size_t)b * 4096 + row) * 768 + h * 64 + col] =
                    f2bf(o_acc[jb][r] * inv[r]);
            }
    } else {
        int fb = blockIdx.x - 2816;
        int bx = fb & 63, b = fb >> 6;
        int r = tid & 63, g = tid >> 6;
        float mc[4], mt = -1e30f;
        #pragma unroll
        for (int c = 0; c < 4; ++c) {
            mc[c] = pm[(size_t)((b * 4 + c) * 64 + bx) * 64 + r];
            mt = fmaxf(mt, mc[c]);
        }
        float fac[4], lt = 0.f;
        #pragma unroll
        for (int c = 0; c < 4; ++c) {
            fac[c] = expf(mc[c] - mt);
            lt += fac[c] * pl[(size_t)((b * 4 + c) * 64 + bx) * 64 + r];
        }
        float inv = 1.0f / lt;
        size_t obase = ((size_t)b * 4096 + (size_t)((bx << 6) + r)) * 768 + 11 * 64 + (g << 4);
        #pragma unroll
        for (int i = 0; i < 16; ++i) {
            float s = 0.f;
            #pragma unroll
            for (int c = 0; c < 4; ++c)
                s += fac[c] * pacc[(size_t)((b * 4 + c) * 64 + bx) * 4096 + (size_t)r * 64 + (g << 4) + i];
            ctxh[obase + i] = f2bf(s * inv);
        }
    }
}

// ---------------------------------------------------------------------------
// K8: proj GEMM — plain bf16 MFMA, BK=64, swizzled LDS, XCD swizzle.
// ---------------------------------------------------------------------------
__global__ __launch_bounds__(256, 2) void gemm_proj_mfma(
    const unsigned short* __restrict__ Xh, const unsigned short* __restrict__ Wh,
    const float* __restrict__ bias, float* __restrict__ out)
{
    __shared__ unsigned short Ah[8192], Bh[8192];
    const int tid = threadIdx.x;
    const int bid = blockIdx.x;
    const int swz = (bid & 7) * 96 + (bid >> 3);
    const int brow = (swz / 6) << 7, bcol = (swz % 6) << 7;
    const int ln = tid & 63, wv = tid >> 6;
    const int wr = (wv >> 1) << 6, wc = (wv & 1) << 6;
    const int srow = tid >> 1;
    const int c0 = (tid & 1) << 2;
    const size_t ag = (size_t)(brow + srow) * 768;
    const size_t bg = (size_t)(bcol + srow) * 768;
    const int fr = ln & 15, fc = ln >> 4;

    f32x4 acc[4][4] = {};
    for (int k0 = 0; k0 < 768; k0 += 64) {
        short8 xa[4], wb[4];
        #pragma unroll
        for (int cc = 0; cc < 4; ++cc) {
            xa[cc] = *(const short8*)(Xh + ag + k0 + ((c0 + cc) << 3));
            wb[cc] = *(const short8*)(Wh + bg + k0 + ((c0 + cc) << 3));
        }
        __syncthreads();
        #pragma unroll
        for (int cc = 0; cc < 4; ++cc) {
            int dst = srow * 64 + (((c0 + cc) ^ (srow & 7)) << 3);
            *(short8*)&Ah[dst] = xa[cc];
            *(short8*)&Bh[dst] = wb[cc];
        }
        __syncthreads();
        #pragma unroll
        for (int ks = 0; ks < 2; ++ks) {
            const int kc = (ks << 2) + fc;
            short8 ah[4], bh[4];
            #pragma unroll
            for (int i = 0; i < 4; ++i) {
                int ar = wr + (i << 4) + fr;
                ah[i] = *(short8*)&Ah[ar * 64 + ((kc ^ (ar & 7)) << 3)];
                int br2 = wc + (i << 4) + fr;
                bh[i] = *(short8*)&Bh[br2 * 64 + ((kc ^ (br2 & 7)) << 3)];
            }
            #pragma unroll
            for (int i = 0; i < 4; ++i)
                #pragma unroll
                for (int j = 0; j < 4; ++j)
                    acc[i][j] = __builtin_amdgcn_mfma_f32_16x16x32_bf16(ah[i], bh[j], acc[i][j], 0, 0, 0);
        }
    }
    const int fg = ln >> 4;
    #pragma unroll
    for (int j = 0; j < 4; ++j) {
        int c = bcol + wc + (j << 4) + fr;
        float bb = bias[c];
        #pragma unroll
        for (int i = 0; i < 4; ++i)
            #pragma unroll
            for (int r = 0; r < 4; ++r) {
                int row = brow + wr + (i << 4) + (fg << 2) + r;
                out[(size_t)row * 768 + c] = acc[i][j][r] + bb;
            }
    }
}

// ---------------------------------------------------------------------------
extern "C" void kernel_launch(void* const* d_in, const int* in_sizes, int n_in,
                              void* d_out, int out_size, void* d_ws, size_t ws_size,
                              hipStream_t stream)
{
    const float* x      = (const float*)d_in[0];
    const float* qkv_w  = (const float*)d_in[1];
    const float* qkv_b  = (const float*)d_in[2];
    const float* proj_w = (const float*)d_in[3];
    const float* proj_b = (const float*)d_in[4];
    float* out = (float*)d_out;

    const size_t QKV = (size_t)4 * 12 * 4096 * 64;   // 12,582,912
    unsigned short* qh = (unsigned short*)d_ws;
    unsigned short* ql = qh + QKV;
    unsigned short* kh = ql + QKV;
    unsigned short* kl = kh + QKV;
    unsigned short* vh = kl + QKV;
    unsigned short* ctxh = vh + QKV;
    float* eB   = (float*)(ctxh + QKV);
    float* denr = eB + 44 * 4096;                     // 16 floats
    float* denc = denr + 16;                          // 16 floats
    float* Wb   = denc + 16;
    float* Tb   = Wb + 44 * 4160;
    unsigned short* Whi  = (unsigned short*)(Tb + 44 * 4160);
    unsigned short* Wlo  = Whi + (size_t)2304 * 768;
    unsigned short* Pwhi = Wlo + (size_t)2304 * 768;
    unsigned short* Pwlo = Pwhi + (size_t)768 * 768;   // written, unused

    unsigned short* Xhi = (unsigned short*)out;
    unsigned short* Xlo = Xhi + QKV;
    float* wacc  = out;                        // 1,441,792
    float* wl    = wacc + 1441792;             // 22,528
    float* wm    = wl + 22528;                 // 22,528
    float* fpacc = wm + 22528;                 // 4,194,304
    float* fpm   = fpacc + 4194304;            // 65,536
    float* fpl   = fpm + 65536;                // 65,536

    hipMemsetAsync(denr, 0, 32 * sizeof(float), stream);
    preconv3<<<2048, 256, 0, stream>>>(x, qkv_w, proj_w,
                                       Xhi, Xlo, Whi, Wlo, Pwhi, Pwlo);
    gemm_qkv2<<<2304, 256, 0, stream>>>(Xhi, Xlo, Whi, Wlo, qkv_b,
                                        qh, ql, kh, kl, vh);
    attn_mega<<<1376, 256, 0, stream>>>(qh, ql, kh, kl, vh,
                                        wacc, wl, wm, fpacc, fpm, fpl);
    wmerge_eb<<<44, 256, 0, stream>>>(wacc, wl, wm, qh, ql, kh, kl,
                                      Wb, eB, denr, denc);
    pinv_pw<<<44, 256, 0, stream>>>(eB, denr, denc, Wb, Tb);
    outp_merge<<<3072, 256, 0, stream>>>(qh, ql, kh, kl, Tb,
                                         fpacc, fpm, fpl, ctxh);
    gemm_proj_mfma<<<768, 256, 0, stream>>>(ctxh, Pwhi, proj_b, out);
}